// Round 3
// baseline (26505.981 us; speedup 1.0000x reference)
//
#include <hip/hip_runtime.h>
#include <stdint.h>

#define T_STEPS 8192
#define IN_DIM  512
#define HID     1024
#define G4      4096
#define NBLK    64          // recurrent blocks (1 per CU, all co-resident)
#define NW      16          // waves per block == h values per block

typedef unsigned long long u64;

// ---------------------------------------------------------------------------
// Kernel 1: x_gates[t][r] = sum_k input[t][k] * W_ih[r][k] + b_ih[r] + b_hh[r]
// fp32 tiled GEMM (NT), 128x128 tile, K-tile 8, 256 threads, 8x8 per thread.
// (unchanged — ~250us, not the bottleneck)
// ---------------------------------------------------------------------------
__global__ __launch_bounds__(256) void gemm_xgates(
    const float* __restrict__ A,    // [8192][512]
    const float* __restrict__ W,    // [4096][512]
    const float* __restrict__ bih,  // [4096]
    const float* __restrict__ bhh,  // [4096]
    float* __restrict__ xg)         // [8192][4096]
{
    __shared__ float At[8][128];   // k-major A tile
    __shared__ float Bt[8][128];   // k-major W tile
    const int tid = threadIdx.x;
    const int r0 = blockIdx.x * 128;   // gate-row dim (4096)
    const int t0 = blockIdx.y * 128;   // time dim (8192)
    const int tx = tid & 15, ty = tid >> 4;
    const int lrow = tid >> 1;         // 0..127
    const int kq   = (tid & 1) * 4;    // 0 or 4

    float acc[8][8];
#pragma unroll
    for (int i = 0; i < 8; ++i)
#pragma unroll
        for (int j = 0; j < 8; ++j) acc[i][j] = 0.f;

    for (int k0 = 0; k0 < IN_DIM; k0 += 8) {
        float4 av = *(const float4*)&A[(size_t)(t0 + lrow) * IN_DIM + k0 + kq];
        float4 bv = *(const float4*)&W[(size_t)(r0 + lrow) * IN_DIM + k0 + kq];
        __syncthreads();
        At[kq + 0][lrow] = av.x; At[kq + 1][lrow] = av.y;
        At[kq + 2][lrow] = av.z; At[kq + 3][lrow] = av.w;
        Bt[kq + 0][lrow] = bv.x; Bt[kq + 1][lrow] = bv.y;
        Bt[kq + 2][lrow] = bv.z; Bt[kq + 3][lrow] = bv.w;
        __syncthreads();
#pragma unroll
        for (int k = 0; k < 8; ++k) {
            float4 a0 = *(const float4*)&At[k][ty * 8];
            float4 a1 = *(const float4*)&At[k][ty * 8 + 4];
            float4 b0 = *(const float4*)&Bt[k][tx * 8];
            float4 b1 = *(const float4*)&Bt[k][tx * 8 + 4];
            float aa[8] = {a0.x, a0.y, a0.z, a0.w, a1.x, a1.y, a1.z, a1.w};
            float bb[8] = {b0.x, b0.y, b0.z, b0.w, b1.x, b1.y, b1.z, b1.w};
#pragma unroll
            for (int i = 0; i < 8; ++i)
#pragma unroll
                for (int j = 0; j < 8; ++j) acc[i][j] += aa[i] * bb[j];
        }
    }

    float bias[8];
#pragma unroll
    for (int j = 0; j < 8; ++j) {
        int r = r0 + tx * 8 + j;
        bias[j] = bih[r] + bhh[r];
    }
#pragma unroll
    for (int i = 0; i < 8; ++i) {
        int t = t0 + ty * 8 + i;
        float4 o0 = make_float4(acc[i][0] + bias[0], acc[i][1] + bias[1],
                                acc[i][2] + bias[2], acc[i][3] + bias[3]);
        float4 o1 = make_float4(acc[i][4] + bias[4], acc[i][5] + bias[5],
                                acc[i][6] + bias[6], acc[i][7] + bias[7]);
        *(float4*)&xg[(size_t)t * G4 + r0 + tx * 8]     = o0;
        *(float4*)&xg[(size_t)t * G4 + r0 + tx * 8 + 4] = o1;
    }
}

// ---------------------------------------------------------------------------
// Kernel 2 (R12): persistent recurrent LSTM — R10 comm core (fixed wave-0
// reducer, register c, reducer-only xg) + three serial-chain cuts:
//   1. LDS atomicAdd (ds_add_f32) accumulation: each wave fadds its 64
//      partials into acc[p][64]; lane 0 bumps cnt[p] (RELEASE orders the
//      fadds first). Reducer spins on ONE counter word and reads the final
//      sum with ONE ds_read — replaces R10's 16-flag spin + 16 strided
//      part loads + 15 adds on the post-last-arrival chain.
//   2. 3-deep poll pipeline (va/vb/vc): detect granularity ~L/3.
//   3. s_setprio(1) on the reducer wave (T5 regime: role-split waves on the
//      same SIMD; reducer wake-up latency is on the global critical cycle).
//
// R11 lessons baked in: NO xg loads on non-reducer waves (vmcnt is in-order;
// a streaming load issued before the poll loads adds its full latency to
// every tag check). Reducer's xn load sits between its fadd and its LDS
// spin (lgkmcnt-only), so it never blocks the spin. c stays in registers
// (quad-replicated in wave 0).
//
// Safety without barriers (tags 1..8192; 0xAA poison can't collide):
//  * acc[p]/cnt[p] reuse at t+2 is >= 2 full LLC flights after the reducer's
//    read+reset (publish(t+2) requires remote detect of t+1, which requires
//    OUR publish of t, issued after the reducer consumed acc/cnt for t).
//  * chunk[w] is wave-private (write/read same wave, DS-ordered).
//  * fadd order is nondeterministic -> reduction reorder noise ~1e-6,
//    threshold 1.45e-2.
// ---------------------------------------------------------------------------
__device__ __forceinline__ float sigm_f(float x) {
    return __builtin_amdgcn_rcpf(1.f + __expf(-x));
}
__device__ __forceinline__ float tanh_f(float x) {
    x = fminf(fmaxf(x, -15.f), 15.f);
    float e = __expf(2.f * x);
    return (e - 1.f) * __builtin_amdgcn_rcpf(e + 1.f);
}

// Broadcast lane q of each 4-lane quad to the whole quad (DPP quad_perm).
// PAT = q | q<<2 | q<<4 | q<<6 : 0x00, 0x55, 0xAA, 0xFF.
template <int PAT>
__device__ __forceinline__ float quad_bcast(float x) {
    int v = __builtin_amdgcn_update_dpp(0, __float_as_int(x), PAT, 0xf, 0xf, true);
    return __int_as_float(v);
}

__global__ __launch_bounds__(1024, 1) void lstm_rec(
    const float* __restrict__ Whh,   // [4096][1024]
    const float* __restrict__ xg,    // [8192][4096]
    float* __restrict__ hs,          // [(T+1)][1024] (rows 1..T used)
    u64* __restrict__ hdata)         // [2][1024] tagged {tag, f32}
{
    __shared__ float    chunk[NW][64];   // per-wave PRIVATE h chunk bounce
    __shared__ float    acc[2][64];      // parity-buffered pre-act accumulators
    __shared__ uint32_t cnt[2];          // parity-buffered arrival counters

    const int tid  = threadIdx.x;
    const int b    = blockIdx.x;         // 0..63
    const int w    = tid >> 6;           // wave 0..15
    const int l    = tid & 63;           // lane
    const int gate = l & 3;              // i,f,g,o
    const int h16  = l >> 2;             // 0..15 — block-local h index
    const int grow = gate * HID + b * NW + h16;   // gate row in [0,4096)

    // Register-resident weight slice: wv[k4] = Whh[grow][64w + 4k4 .. +3].
    float4 wv[16];
    {
        const float* row = &Whh[(size_t)grow * HID + 64 * w];
#pragma unroll
        for (int k4 = 0; k4 < 16; ++k4) wv[k4] = *(const float4*)&row[4 * k4];
    }
#pragma unroll
    for (int k4 = 0; k4 < 16; ++k4)
        asm volatile("" : "+v"(wv[k4].x), "+v"(wv[k4].y),
                         "+v"(wv[k4].z), "+v"(wv[k4].w));

    if (tid < 2 * 64) ((float*)acc)[tid] = 0.f;
    if (tid < 2) cnt[tid] = 0;
    __syncthreads();    // the ONLY barrier (orders acc/cnt init)

    const bool is_red = (w == 0);
    if (is_red) __builtin_amdgcn_s_setprio(1);   // reducer wake-up is on the
                                                 // block's critical chain
    float c  = 0.f;                      // quad-replicated cell state (wave 0)
    float xv = 0.f, xn = 0.f;            // x-gates (reducer only)
    if (is_red) xv = xg[grow];           // t = 0

    for (int t = 0; t < T_STEPS; ++t) {
        const int p = t & 1;

        float a0 = 0.f, a1 = 0.f, a2 = 0.f, a3 = 0.f;
        if (t > 0) {
            // ---- acquire own chunk: 1 tagged load/lane, 3-deep pipeline ---
            const u64* ptr = hdata + (((size_t)(t - 1) & 1) << 10) + 64 * w + l;
            const uint32_t want32 = (uint32_t)t;
            u64 va = __hip_atomic_load(ptr, __ATOMIC_RELAXED, __HIP_MEMORY_SCOPE_AGENT);
            u64 vb = __hip_atomic_load(ptr, __ATOMIC_RELAXED, __HIP_MEMORY_SCOPE_AGENT);
            u64 vc = __hip_atomic_load(ptr, __ATOMIC_RELAXED, __HIP_MEMORY_SCOPE_AGENT);
            u64 v;
            for (;;) {
                if (__all((uint32_t)(va >> 32) == want32)) { v = va; break; }
                va = __hip_atomic_load(ptr, __ATOMIC_RELAXED, __HIP_MEMORY_SCOPE_AGENT);
                if (__all((uint32_t)(vb >> 32) == want32)) { v = vb; break; }
                vb = __hip_atomic_load(ptr, __ATOMIC_RELAXED, __HIP_MEMORY_SCOPE_AGENT);
                if (__all((uint32_t)(vc >> 32) == want32)) { v = vc; break; }
                vc = __hip_atomic_load(ptr, __ATOMIC_RELAXED, __HIP_MEMORY_SCOPE_AGENT);
            }
            // ---- partial dot over own 64 columns (LDS broadcast reads) ----
            chunk[w][l] = __uint_as_float((uint32_t)v);
#pragma unroll
            for (int k4 = 0; k4 < 16; ++k4) {
                float4 h4 = *(const float4*)&chunk[w][4 * k4];  // wave-uniform
                a0 = fmaf(wv[k4].x, h4.x, a0);
                a1 = fmaf(wv[k4].y, h4.y, a1);
                a2 = fmaf(wv[k4].z, h4.z, a2);
                a3 = fmaf(wv[k4].w, h4.w, a3);
            }
        }
        // ---- deposit: hardware-summed partial + arrival count --------------
        atomicAdd(&acc[p][l], (a0 + a1) + (a2 + a3));   // ds_add, 2 lanes/bank
        if (l == 0)
            __hip_atomic_fetch_add(&cnt[p], 1u, __ATOMIC_RELEASE,
                                   __HIP_MEMORY_SCOPE_WORKGROUP);
        // Non-reducer waves fall straight into the next step's poll.

        if (is_red) {
            if (t + 1 < T_STEPS)                  // vmcnt load, hidden under
                xn = xg[(size_t)(t + 1) * G4 + grow];   // the lgkmcnt-only spin
            while (__hip_atomic_load(&cnt[p], __ATOMIC_ACQUIRE,
                                     __HIP_MEMORY_SCOPE_WORKGROUP) != NW) { }
            float pre = acc[p][l] + xv;           // ONE ds_read
            acc[p][l] = 0.f;                      // re-arm for t+2
            if (l == 0) cnt[p] = 0;
            // quad exchange: every lane of a quad gets all 4 gate pre-acts
            float pi = quad_bcast<0x00>(pre);
            float pf = quad_bcast<0x55>(pre);
            float pg = quad_bcast<0xAA>(pre);
            float po = quad_bcast<0xFF>(pre);
            float ig = sigm_f(pi), fg = sigm_f(pf);
            float gv = tanh_f(pg), og = sigm_f(po);
            c = fg * c + ig * gv;                 // identical across quad
            float h = og * tanh_f(c);
            const uint32_t tag = (uint32_t)(t + 1);
            if (gate == 0) {                      // 16 lanes, one 128B line
                u64 pub = ((u64)tag << 32) | (u64)__float_as_uint(h);
                __hip_atomic_store(&hdata[((size_t)p << 10) + b * NW + h16], pub,
                                   __ATOMIC_RELAXED, __HIP_MEMORY_SCOPE_AGENT);
                hs[(size_t)(t + 1) * HID + b * NW + h16] = h;  // epilogue copy
            }
            xv = xn;
        }
    }
}

// ---------------------------------------------------------------------------
// Kernel 3: logits = hs @ W_lin^T + b_lin ; softmax over O=2. (unchanged)
// ---------------------------------------------------------------------------
__global__ __launch_bounds__(256) void proj_softmax(
    const float* __restrict__ hs,    // [(T+1)][1024], rows 1..T are h_t
    const float* __restrict__ Wl,    // [2][1024]
    const float* __restrict__ bl,    // [2]
    float* __restrict__ out)         // [T][2]
{
    const int tid = threadIdx.x;
    const int w = tid >> 6, l = tid & 63;
    const int row = blockIdx.x * 4 + w;            // 0..8191
    const float* h = &hs[(size_t)(row + 1) * HID];

    float a0 = 0.f, a1 = 0.f;
#pragma unroll
    for (int i = 0; i < 4; ++i) {
        float4 hv = *(const float4*)&h[256 * i + 4 * l];
        float4 w0 = *(const float4*)&Wl[256 * i + 4 * l];
        float4 w1 = *(const float4*)&Wl[HID + 256 * i + 4 * l];
        a0 = fmaf(hv.x, w0.x, a0); a0 = fmaf(hv.y, w0.y, a0);
        a0 = fmaf(hv.z, w0.z, a0); a0 = fmaf(hv.w, w0.w, a0);
        a1 = fmaf(hv.x, w1.x, a1); a1 = fmaf(hv.y, w1.y, a1);
        a1 = fmaf(hv.z, w1.z, a1); a1 = fmaf(hv.w, w1.w, a1);
    }
#pragma unroll
    for (int off = 1; off < 64; off <<= 1) {
        a0 += __shfl_xor(a0, off, 64);
        a1 += __shfl_xor(a1, off, 64);
    }
    if (l == 0) {
        float l0 = a0 + bl[0];
        float l1 = a1 + bl[1];
        float m  = fmaxf(l0, l1);
        float e0 = __expf(l0 - m), e1 = __expf(l1 - m);
        float inv = 1.f / (e0 + e1);
        float2 o = make_float2(e0 * inv, e1 * inv);
        *(float2*)&out[(size_t)row * 2] = o;
    }
}

// ---------------------------------------------------------------------------
extern "C" void kernel_launch(void* const* d_in, const int* in_sizes, int n_in,
                              void* d_out, int out_size, void* d_ws, size_t ws_size,
                              hipStream_t stream)
{
    const float* input = (const float*)d_in[0];   // [8192][512]
    const float* W_ih  = (const float*)d_in[1];   // [4096][512]
    const float* W_hh  = (const float*)d_in[2];   // [4096][1024]
    const float* b_ih  = (const float*)d_in[3];   // [4096]
    const float* b_hh  = (const float*)d_in[4];   // [4096]
    const float* W_lin = (const float*)d_in[5];   // [2][1024]
    const float* b_lin = (const float*)d_in[6];   // [2]
    float* out = (float*)d_out;                   // [8192][2]

    char* ws = (char*)d_ws;
    float* hs     = (float*)ws;                          // (T+1)*1024 f32
    size_t hs_b   = (size_t)(T_STEPS + 1) * HID * sizeof(float);
    u64*   hdata  = (u64*)(ws + hs_b);                   // 2*1024 u64
    size_t hd_b   = 2 * 1024 * sizeof(u64);
    float* xg     = (float*)(ws + hs_b + hd_b);          // T*4096 f32

    // No memsets needed: 0xAA poison (0xAAAAAAAA) never equals a valid tag
    // (1..8192), hs row 0 is never read, and t=0 uses in-register zeros.

    dim3 g1(G4 / 128, T_STEPS / 128);
    gemm_xgates<<<g1, 256, 0, stream>>>(input, W_ih, b_ih, b_hh, xg);

    lstm_rec<<<NBLK, NW * 64, 0, stream>>>(W_hh, xg, hs, hdata);

    proj_softmax<<<T_STEPS / 4, 256, 0, stream>>>(hs, W_lin, b_lin, out);
}

// Round 4
// 23867.410 us; speedup vs baseline: 1.1106x; 1.1106x over previous
//
#include <hip/hip_runtime.h>
#include <stdint.h>

#define T_STEPS 8192
#define IN_DIM  512
#define HID     1024
#define G4      4096
#define NBLK    64          // recurrent blocks (1 per CU, all co-resident)
#define NW      16          // waves per block == h values per block

typedef unsigned long long u64;

// ---------------------------------------------------------------------------
// Kernel 1: x_gates[t][r] = sum_k input[t][k] * W_ih[r][k] + b_ih[r] + b_hh[r]
// fp32 tiled GEMM (NT), 128x128 tile, K-tile 8, 256 threads, 8x8 per thread.
// (unchanged — ~250us, not the bottleneck)
// ---------------------------------------------------------------------------
__global__ __launch_bounds__(256) void gemm_xgates(
    const float* __restrict__ A,    // [8192][512]
    const float* __restrict__ W,    // [4096][512]
    const float* __restrict__ bih,  // [4096]
    const float* __restrict__ bhh,  // [4096]
    float* __restrict__ xg)         // [8192][4096]
{
    __shared__ float At[8][128];   // k-major A tile
    __shared__ float Bt[8][128];   // k-major W tile
    const int tid = threadIdx.x;
    const int r0 = blockIdx.x * 128;   // gate-row dim (4096)
    const int t0 = blockIdx.y * 128;   // time dim (8192)
    const int tx = tid & 15, ty = tid >> 4;
    const int lrow = tid >> 1;         // 0..127
    const int kq   = (tid & 1) * 4;    // 0 or 4

    float acc[8][8];
#pragma unroll
    for (int i = 0; i < 8; ++i)
#pragma unroll
        for (int j = 0; j < 8; ++j) acc[i][j] = 0.f;

    for (int k0 = 0; k0 < IN_DIM; k0 += 8) {
        float4 av = *(const float4*)&A[(size_t)(t0 + lrow) * IN_DIM + k0 + kq];
        float4 bv = *(const float4*)&W[(size_t)(r0 + lrow) * IN_DIM + k0 + kq];
        __syncthreads();
        At[kq + 0][lrow] = av.x; At[kq + 1][lrow] = av.y;
        At[kq + 2][lrow] = av.z; At[kq + 3][lrow] = av.w;
        Bt[kq + 0][lrow] = bv.x; Bt[kq + 1][lrow] = bv.y;
        Bt[kq + 2][lrow] = bv.z; Bt[kq + 3][lrow] = bv.w;
        __syncthreads();
#pragma unroll
        for (int k = 0; k < 8; ++k) {
            float4 a0 = *(const float4*)&At[k][ty * 8];
            float4 a1 = *(const float4*)&At[k][ty * 8 + 4];
            float4 b0 = *(const float4*)&Bt[k][tx * 8];
            float4 b1 = *(const float4*)&Bt[k][tx * 8 + 4];
            float aa[8] = {a0.x, a0.y, a0.z, a0.w, a1.x, a1.y, a1.z, a1.w};
            float bb[8] = {b0.x, b0.y, b0.z, b0.w, b1.x, b1.y, b1.z, b1.w};
#pragma unroll
            for (int i = 0; i < 8; ++i)
#pragma unroll
                for (int j = 0; j < 8; ++j) acc[i][j] += aa[i] * bb[j];
        }
    }

    float bias[8];
#pragma unroll
    for (int j = 0; j < 8; ++j) {
        int r = r0 + tx * 8 + j;
        bias[j] = bih[r] + bhh[r];
    }
#pragma unroll
    for (int i = 0; i < 8; ++i) {
        int t = t0 + ty * 8 + i;
        float4 o0 = make_float4(acc[i][0] + bias[0], acc[i][1] + bias[1],
                                acc[i][2] + bias[2], acc[i][3] + bias[3]);
        float4 o1 = make_float4(acc[i][4] + bias[4], acc[i][5] + bias[5],
                                acc[i][6] + bias[6], acc[i][7] + bias[7]);
        *(float4*)&xg[(size_t)t * G4 + r0 + tx * 8]     = o0;
        *(float4*)&xg[(size_t)t * G4 + r0 + tx * 8 + 4] = o1;
    }
}

// ---------------------------------------------------------------------------
// Kernel 2 (R13): persistent recurrent LSTM — R10 comm core EXACTLY
// (part stores + per-wave release flag + fixed wave-0 reducer + register c,
// the empirical best at 16.0ms; R11 ticket and R12 ds_add both regressed),
// with ONE wave-local change: ARRIVAL-ORDER CHUNKED processing.
//
// Wave w's 64 slots = 4 x 128B lines, line j produced by block 4w+j. R10
// waited for all 4 producers (__all over 64 lanes) before ANY dot work; in
// the all-to-all max-of-64 convoy, per-producer skew was pure idle time.
// R13: per-lane tagged poll (2-deep), per-16-lane-group ballot detection,
// and each line is FMA'd the moment it lands (separate accumulator per
// chunk; final combine in fixed order -> deterministic numerics). After the
// LAST line arrives only ~16 FMAs + deposit remain, and straggler wait is
// converted into useful work.
//
// R11/R12 lessons enforced: no vmem loads between poll loads and their tag
// checks on non-reducer waves; no LDS RMW atomics in the deposit; no
// always-on setprio; reducer's xg prefetch sits between its deposit and its
// LDS-only (lgkmcnt) flag spin.
//
// Safety without barriers (tags 1..8192; 0xAA poison can't collide):
//  * part[p]/pflag[p] reuse at t+2 is >= 2 full LLC flights after the
//    reducer consumed them for t (publish(t+2) requires remote detect of
//    t+1, which requires OUR publish of t, issued after the reducer's part
//    reads).
//  * chunk[w] is wave-private: exec-masked ds_write at detection precedes
//    the wave's ds_read broadcasts in program order (same-wave DS ordering).
// ---------------------------------------------------------------------------
__device__ __forceinline__ float sigm_f(float x) {
    return __builtin_amdgcn_rcpf(1.f + __expf(-x));
}
__device__ __forceinline__ float tanh_f(float x) {
    x = fminf(fmaxf(x, -15.f), 15.f);
    float e = __expf(2.f * x);
    return (e - 1.f) * __builtin_amdgcn_rcpf(e + 1.f);
}

// Broadcast lane q of each 4-lane quad to the whole quad (DPP quad_perm).
// PAT = q | q<<2 | q<<4 | q<<6 : 0x00, 0x55, 0xAA, 0xFF.
template <int PAT>
__device__ __forceinline__ float quad_bcast(float x) {
    int v = __builtin_amdgcn_update_dpp(0, __float_as_int(x), PAT, 0xf, 0xf, true);
    return __int_as_float(v);
}

__global__ __launch_bounds__(1024, 1) void lstm_rec(
    const float* __restrict__ Whh,   // [4096][1024]
    const float* __restrict__ xg,    // [8192][4096]
    float* __restrict__ hs,          // [(T+1)][1024] (rows 1..T used)
    u64* __restrict__ hdata)         // [2][1024] tagged {tag, f32}
{
    __shared__ float    chunk[NW][64];     // per-wave PRIVATE h chunk bounce
    __shared__ float    part[2][NW][64];   // parity-buffered partial sums
    __shared__ uint32_t pflag[2][NW];      // parity-buffered tag flags

    const int tid  = threadIdx.x;
    const int b    = blockIdx.x;           // 0..63
    const int w    = tid >> 6;             // wave 0..15
    const int l    = tid & 63;             // lane
    const int gate = l & 3;                // i,f,g,o
    const int h16  = l >> 2;               // 0..15 — block-local h index
    const int grow = gate * HID + b * NW + h16;   // gate row in [0,4096)

    // Register-resident weight slice: wv[k4] = Whh[grow][64w + 4k4 .. +3].
    float4 wv[16];
    {
        const float* row = &Whh[(size_t)grow * HID + 64 * w];
#pragma unroll
        for (int k4 = 0; k4 < 16; ++k4) wv[k4] = *(const float4*)&row[4 * k4];
    }
#pragma unroll
    for (int k4 = 0; k4 < 16; ++k4)
        asm volatile("" : "+v"(wv[k4].x), "+v"(wv[k4].y),
                         "+v"(wv[k4].z), "+v"(wv[k4].w));

    if (tid < 2 * NW) ((uint32_t*)pflag)[tid] = 0;
    __syncthreads();    // the ONLY barrier (orders pflag init)

    const bool is_red = (w == 0);
    float c  = 0.f;                        // quad-replicated cell state (wave 0)
    float xv = 0.f, xn = 0.f;              // x-gates (reducer only)
    if (is_red) xv = xg[grow];             // t = 0

    for (int t = 0; t < T_STEPS; ++t) {
        const int p = t & 1;

        float cj0 = 0.f, cj1 = 0.f, cj2 = 0.f, cj3 = 0.f;
        if (t > 0) {
            // ---- acquire own chunk, arrival-order: per-lane 2-deep tagged
            // poll, per-line ballot detection, immediate per-chunk FMA. ----
            const u64* ptr = hdata + (((size_t)(t - 1) & 1) << 10) + 64 * w + l;
            const uint32_t want32 = (uint32_t)t;
            u64 va = __hip_atomic_load(ptr, __ATOMIC_RELAXED, __HIP_MEMORY_SCOPE_AGENT);
            u64 vb = __hip_atomic_load(ptr, __ATOMIC_RELAXED, __HIP_MEMORY_SCOPE_AGENT);
            bool val = false;
            uint32_t done = 0;
            float cj[4] = {0.f, 0.f, 0.f, 0.f};
            for (;;) {
                if (!val && (uint32_t)(va >> 32) == want32) {
                    chunk[w][l] = __uint_as_float((uint32_t)va);  // exec-masked
                    val = true;
                }
                u64 ball = __ballot(val);
#pragma unroll
                for (int j = 0; j < 4; ++j) {
                    const u64 gm = 0xFFFFull << (16 * j);
                    if (!(done & (1u << j)) && (ball & gm) == gm) {
                        float s0 = 0.f, s1 = 0.f, s2 = 0.f, s3 = 0.f;
#pragma unroll
                        for (int k4 = 4 * j; k4 < 4 * j + 4; ++k4) {
                            float4 h4 = *(const float4*)&chunk[w][4 * k4];
                            s0 = fmaf(wv[k4].x, h4.x, s0);
                            s1 = fmaf(wv[k4].y, h4.y, s1);
                            s2 = fmaf(wv[k4].z, h4.z, s2);
                            s3 = fmaf(wv[k4].w, h4.w, s3);
                        }
                        cj[j] = (s0 + s1) + (s2 + s3);
                        done |= 1u << j;
                    }
                }
                if (done == 0xFu) break;
                va = vb;
                if (!val)
                    vb = __hip_atomic_load(ptr, __ATOMIC_RELAXED, __HIP_MEMORY_SCOPE_AGENT);
            }
            cj0 = cj[0]; cj1 = cj[1]; cj2 = cj[2]; cj3 = cj[3];
        }
        // ---- deposit (EXACT R10): part store + lane-0 release flag --------
        part[p][w][l] = (cj0 + cj1) + (cj2 + cj3);   // fixed-order combine
        if (l == 0)
            __hip_atomic_store(&pflag[p][w], (uint32_t)(t + 1),
                               __ATOMIC_RELEASE, __HIP_MEMORY_SCOPE_WORKGROUP);
        // Non-reducer waves fall straight into the next step's poll.

        if (is_red) {
            if (t + 1 < T_STEPS)                  // vmcnt load, hidden under
                xn = xg[(size_t)(t + 1) * G4 + grow];   // the lgkmcnt-only spin
            const uint32_t fw = (uint32_t)(t + 1);
            for (;;) {
                uint32_t f = (l < NW)
                    ? __hip_atomic_load(&pflag[p][l], __ATOMIC_ACQUIRE,
                                        __HIP_MEMORY_SCOPE_WORKGROUP)
                    : fw;
                if (__all(f == fw)) break;
            }
            float s0 = 0.f, s1 = 0.f, s2 = 0.f, s3 = 0.f;
#pragma unroll
            for (int ww = 0; ww < NW; ww += 4) {
                s0 += part[p][ww + 0][l];
                s1 += part[p][ww + 1][l];
                s2 += part[p][ww + 2][l];
                s3 += part[p][ww + 3][l];
            }
            float pre = ((s0 + s1) + (s2 + s3)) + xv;
            // quad exchange: every lane of a quad gets all 4 gate pre-acts
            float pi = quad_bcast<0x00>(pre);
            float pf = quad_bcast<0x55>(pre);
            float pg = quad_bcast<0xAA>(pre);
            float po = quad_bcast<0xFF>(pre);
            float ig = sigm_f(pi), fg = sigm_f(pf);
            float gv = tanh_f(pg), og = sigm_f(po);
            c = fg * c + ig * gv;                 // identical across quad
            float h = og * tanh_f(c);
            const uint32_t tag = (uint32_t)(t + 1);
            if (gate == 0) {                      // 16 lanes, one 128B line
                u64 pub = ((u64)tag << 32) | (u64)__float_as_uint(h);
                __hip_atomic_store(&hdata[((size_t)p << 10) + b * NW + h16], pub,
                                   __ATOMIC_RELAXED, __HIP_MEMORY_SCOPE_AGENT);
                hs[(size_t)(t + 1) * HID + b * NW + h16] = h;  // epilogue copy
            }
            xv = xn;
        }
    }
}

// ---------------------------------------------------------------------------
// Kernel 3: logits = hs @ W_lin^T + b_lin ; softmax over O=2. (unchanged)
// ---------------------------------------------------------------------------
__global__ __launch_bounds__(256) void proj_softmax(
    const float* __restrict__ hs,    // [(T+1)][1024], rows 1..T are h_t
    const float* __restrict__ Wl,    // [2][1024]
    const float* __restrict__ bl,    // [2]
    float* __restrict__ out)         // [T][2]
{
    const int tid = threadIdx.x;
    const int w = tid >> 6, l = tid & 63;
    const int row = blockIdx.x * 4 + w;            // 0..8191
    const float* h = &hs[(size_t)(row + 1) * HID];

    float a0 = 0.f, a1 = 0.f;
#pragma unroll
    for (int i = 0; i < 4; ++i) {
        float4 hv = *(const float4*)&h[256 * i + 4 * l];
        float4 w0 = *(const float4*)&Wl[256 * i + 4 * l];
        float4 w1 = *(const float4*)&Wl[HID + 256 * i + 4 * l];
        a0 = fmaf(hv.x, w0.x, a0); a0 = fmaf(hv.y, w0.y, a0);
        a0 = fmaf(hv.z, w0.z, a0); a0 = fmaf(hv.w, w0.w, a0);
        a1 = fmaf(hv.x, w1.x, a1); a1 = fmaf(hv.y, w1.y, a1);
        a1 = fmaf(hv.z, w1.z, a1); a1 = fmaf(hv.w, w1.w, a1);
    }
#pragma unroll
    for (int off = 1; off < 64; off <<= 1) {
        a0 += __shfl_xor(a0, off, 64);
        a1 += __shfl_xor(a1, off, 64);
    }
    if (l == 0) {
        float l0 = a0 + bl[0];
        float l1 = a1 + bl[1];
        float m  = fmaxf(l0, l1);
        float e0 = __expf(l0 - m), e1 = __expf(l1 - m);
        float inv = 1.f / (e0 + e1);
        float2 o = make_float2(e0 * inv, e1 * inv);
        *(float2*)&out[(size_t)row * 2] = o;
    }
}

// ---------------------------------------------------------------------------
extern "C" void kernel_launch(void* const* d_in, const int* in_sizes, int n_in,
                              void* d_out, int out_size, void* d_ws, size_t ws_size,
                              hipStream_t stream)
{
    const float* input = (const float*)d_in[0];   // [8192][512]
    const float* W_ih  = (const float*)d_in[1];   // [4096][512]
    const float* W_hh  = (const float*)d_in[2];   // [4096][1024]
    const float* b_ih  = (const float*)d_in[3];   // [4096]
    const float* b_hh  = (const float*)d_in[4];   // [4096]
    const float* W_lin = (const float*)d_in[5];   // [2][1024]
    const float* b_lin = (const float*)d_in[6];   // [2]
    float* out = (float*)d_out;                   // [8192][2]

    char* ws = (char*)d_ws;
    float* hs     = (float*)ws;                          // (T+1)*1024 f32
    size_t hs_b   = (size_t)(T_STEPS + 1) * HID * sizeof(float);
    u64*   hdata  = (u64*)(ws + hs_b);                   // 2*1024 u64
    size_t hd_b   = 2 * 1024 * sizeof(u64);
    float* xg     = (float*)(ws + hs_b + hd_b);          // T*4096 f32

    // No memsets needed: 0xAA poison (0xAAAAAAAA) never equals a valid tag
    // (1..8192), hs row 0 is never read, and t=0 uses in-register zeros.

    dim3 g1(G4 / 128, T_STEPS / 128);
    gemm_xgates<<<g1, 256, 0, stream>>>(input, W_ih, b_ih, b_hh, xg);

    lstm_rec<<<NBLK, NW * 64, 0, stream>>>(W_hh, xg, hs, hdata);

    proj_softmax<<<T_STEPS / 4, 256, 0, stream>>>(hs, W_lin, b_lin, out);
}

// Round 5
// 16689.281 us; speedup vs baseline: 1.5882x; 1.4301x over previous
//
#include <hip/hip_runtime.h>
#include <stdint.h>

#define T_STEPS 8192
#define IN_DIM  512
#define HID     1024
#define G4      4096
#define NBLK    64          // recurrent blocks (1 per CU, all co-resident)
#define NW      16          // waves per block == h values per block

typedef unsigned long long u64;

// ---------------------------------------------------------------------------
// Kernel 1: x_gates[t][r] = sum_k input[t][k] * W_ih[r][k] + b_ih[r] + b_hh[r]
// fp32 tiled GEMM (NT), 128x128 tile, K-tile 8, 256 threads, 8x8 per thread.
// (unchanged — ~250us, not the bottleneck)
// ---------------------------------------------------------------------------
__global__ __launch_bounds__(256) void gemm_xgates(
    const float* __restrict__ A,    // [8192][512]
    const float* __restrict__ W,    // [4096][512]
    const float* __restrict__ bih,  // [4096]
    const float* __restrict__ bhh,  // [4096]
    float* __restrict__ xg)         // [8192][4096]
{
    __shared__ float At[8][128];   // k-major A tile
    __shared__ float Bt[8][128];   // k-major W tile
    const int tid = threadIdx.x;
    const int r0 = blockIdx.x * 128;   // gate-row dim (4096)
    const int t0 = blockIdx.y * 128;   // time dim (8192)
    const int tx = tid & 15, ty = tid >> 4;
    const int lrow = tid >> 1;         // 0..127
    const int kq   = (tid & 1) * 4;    // 0 or 4

    float acc[8][8];
#pragma unroll
    for (int i = 0; i < 8; ++i)
#pragma unroll
        for (int j = 0; j < 8; ++j) acc[i][j] = 0.f;

    for (int k0 = 0; k0 < IN_DIM; k0 += 8) {
        float4 av = *(const float4*)&A[(size_t)(t0 + lrow) * IN_DIM + k0 + kq];
        float4 bv = *(const float4*)&W[(size_t)(r0 + lrow) * IN_DIM + k0 + kq];
        __syncthreads();
        At[kq + 0][lrow] = av.x; At[kq + 1][lrow] = av.y;
        At[kq + 2][lrow] = av.z; At[kq + 3][lrow] = av.w;
        Bt[kq + 0][lrow] = bv.x; Bt[kq + 1][lrow] = bv.y;
        Bt[kq + 2][lrow] = bv.z; Bt[kq + 3][lrow] = bv.w;
        __syncthreads();
#pragma unroll
        for (int k = 0; k < 8; ++k) {
            float4 a0 = *(const float4*)&At[k][ty * 8];
            float4 a1 = *(const float4*)&At[k][ty * 8 + 4];
            float4 b0 = *(const float4*)&Bt[k][tx * 8];
            float4 b1 = *(const float4*)&Bt[k][tx * 8 + 4];
            float aa[8] = {a0.x, a0.y, a0.z, a0.w, a1.x, a1.y, a1.z, a1.w};
            float bb[8] = {b0.x, b0.y, b0.z, b0.w, b1.x, b1.y, b1.z, b1.w};
#pragma unroll
            for (int i = 0; i < 8; ++i)
#pragma unroll
                for (int j = 0; j < 8; ++j) acc[i][j] += aa[i] * bb[j];
        }
    }

    float bias[8];
#pragma unroll
    for (int j = 0; j < 8; ++j) {
        int r = r0 + tx * 8 + j;
        bias[j] = bih[r] + bhh[r];
    }
#pragma unroll
    for (int i = 0; i < 8; ++i) {
        int t = t0 + ty * 8 + i;
        float4 o0 = make_float4(acc[i][0] + bias[0], acc[i][1] + bias[1],
                                acc[i][2] + bias[2], acc[i][3] + bias[3]);
        float4 o1 = make_float4(acc[i][4] + bias[4], acc[i][5] + bias[5],
                                acc[i][6] + bias[6], acc[i][7] + bias[7]);
        *(float4*)&xg[(size_t)t * G4 + r0 + tx * 8]     = o0;
        *(float4*)&xg[(size_t)t * G4 + r0 + tx * 8 + 4] = o1;
    }
}

// ---------------------------------------------------------------------------
// Kernel 2 (R14): EXACT R10 comm core — the empirical best (16.0ms steady;
// R11 ticket / R12 ds_add / R13 arrival-order all regressed) — with ONE
// change: the publish is an RMW atomic EXCHANGE, not an atomic store.
//
// Why: rocprof shows WRITE_SIZE = 98.3MB = hs(33.5MB) + hdata publishes
// (64 blk x 128B x 8192 = 64MB) — the agent-scope atomic STORE writes
// through to HBM and (with FETCH ~280MB above the streaming inputs) the
// exchange lines do not stay LLC-resident, so consumer polls pay HBM-class
// RT (~900cy), not LLC-class (~500cy). An RMW atomic is performed AT the
// scope's cache point (LLC for agent) and leaves the 16KB hdata buffer
// allocated-dirty in LLC. Falsifiable: WRITE_SIZE must drop to ~34MB.
//
// Everything else byte-identical to R10:
//  * wave w polls ONLY h[64w..64w+64) — 1 tagged u64 load/lane, 2-deep.
//  * lane l owns (gate=l&3, h16=l>>2); 64 f32 weights/lane; chunk bounced
//    through private LDS, consumed as wave-uniform ds_read_b128 broadcasts.
//  * partial -> part[p] store + lane-0 RELEASE flag; fixed wave-0 reducer
//    spins on the 16 flags (LDS-only), 16-load reduce, quad_perm gate
//    exchange, register c, single-line publish + hs epilogue copy.
//  * no xg loads on non-reducer waves (vmcnt is in-order — R11 lesson);
//    no LDS RMW in deposit (R12); no always-on setprio (R12); minimal
//    poll loop body (R13).
//
// Self-timing safety unchanged (tags 1..8192; 0xAA poison can't collide;
// part/pflag parity reuse separated by >=2 LLC flights; chunk wave-private).
// ---------------------------------------------------------------------------
__device__ __forceinline__ float sigm_f(float x) {
    return __builtin_amdgcn_rcpf(1.f + __expf(-x));
}
__device__ __forceinline__ float tanh_f(float x) {
    x = fminf(fmaxf(x, -15.f), 15.f);
    float e = __expf(2.f * x);
    return (e - 1.f) * __builtin_amdgcn_rcpf(e + 1.f);
}

// Broadcast lane q of each 4-lane quad to the whole quad (DPP quad_perm).
// PAT = q | q<<2 | q<<4 | q<<6 : 0x00, 0x55, 0xAA, 0xFF.
template <int PAT>
__device__ __forceinline__ float quad_bcast(float x) {
    int v = __builtin_amdgcn_update_dpp(0, __float_as_int(x), PAT, 0xf, 0xf, true);
    return __int_as_float(v);
}

__global__ __launch_bounds__(1024, 1) void lstm_rec(
    const float* __restrict__ Whh,   // [4096][1024]
    const float* __restrict__ xg,    // [8192][4096]
    float* __restrict__ hs,          // [(T+1)][1024] (rows 1..T used)
    u64* __restrict__ hdata)         // [2][1024] tagged {tag, f32}
{
    __shared__ float    chunk[NW][64];     // per-wave PRIVATE h chunk bounce
    __shared__ float    part[2][NW][64];   // parity-buffered partial sums
    __shared__ uint32_t pflag[2][NW];      // parity-buffered tag flags

    const int tid  = threadIdx.x;
    const int b    = blockIdx.x;           // 0..63
    const int w    = tid >> 6;             // wave 0..15
    const int l    = tid & 63;             // lane
    const int gate = l & 3;                // i,f,g,o
    const int h16  = l >> 2;               // 0..15 — block-local h index
    const int grow = gate * HID + b * NW + h16;   // gate row in [0,4096)

    // Register-resident weight slice: wv[k4] = Whh[grow][64w + 4k4 .. +3].
    float4 wv[16];
    {
        const float* row = &Whh[(size_t)grow * HID + 64 * w];
#pragma unroll
        for (int k4 = 0; k4 < 16; ++k4) wv[k4] = *(const float4*)&row[4 * k4];
    }
#pragma unroll
    for (int k4 = 0; k4 < 16; ++k4)
        asm volatile("" : "+v"(wv[k4].x), "+v"(wv[k4].y),
                         "+v"(wv[k4].z), "+v"(wv[k4].w));

    if (tid < 2 * NW) ((uint32_t*)pflag)[tid] = 0;
    __syncthreads();    // the ONLY barrier (orders pflag init)

    const bool is_red = (w == 0);
    float c  = 0.f;                        // quad-replicated cell state (wave 0)
    float xv = 0.f, xn = 0.f;              // x-gates (reducer only)
    if (is_red) xv = xg[grow];             // t = 0

    for (int t = 0; t < T_STEPS; ++t) {
        const int p = t & 1;

        float a0 = 0.f, a1 = 0.f, a2 = 0.f, a3 = 0.f;
        if (t > 0) {
            // ---- acquire own chunk: 1 tagged load/lane, 2-deep pipeline ---
            const u64* ptr = hdata + (((size_t)(t - 1) & 1) << 10) + 64 * w + l;
            const uint32_t want32 = (uint32_t)t;
            u64 va = __hip_atomic_load(ptr, __ATOMIC_RELAXED, __HIP_MEMORY_SCOPE_AGENT);
            u64 vb = __hip_atomic_load(ptr, __ATOMIC_RELAXED, __HIP_MEMORY_SCOPE_AGENT);
            u64 v;
            for (;;) {
                if (__all((uint32_t)(va >> 32) == want32)) { v = va; break; }
                va = __hip_atomic_load(ptr, __ATOMIC_RELAXED, __HIP_MEMORY_SCOPE_AGENT);
                if (__all((uint32_t)(vb >> 32) == want32)) { v = vb; break; }
                vb = __hip_atomic_load(ptr, __ATOMIC_RELAXED, __HIP_MEMORY_SCOPE_AGENT);
            }
            // ---- partial dot over own 64 columns (LDS broadcast reads) ----
            chunk[w][l] = __uint_as_float((uint32_t)v);
#pragma unroll
            for (int k4 = 0; k4 < 16; ++k4) {
                float4 h4 = *(const float4*)&chunk[w][4 * k4];  // wave-uniform
                a0 = fmaf(wv[k4].x, h4.x, a0);
                a1 = fmaf(wv[k4].y, h4.y, a1);
                a2 = fmaf(wv[k4].z, h4.z, a2);
                a3 = fmaf(wv[k4].w, h4.w, a3);
            }
        }
        // ---- deposit (R10): part store + lane-0 release flag --------------
        part[p][w][l] = (a0 + a1) + (a2 + a3);
        if (l == 0)
            __hip_atomic_store(&pflag[p][w], (uint32_t)(t + 1),
                               __ATOMIC_RELEASE, __HIP_MEMORY_SCOPE_WORKGROUP);
        // Non-reducer waves fall straight into the next step's poll.

        if (is_red) {
            if (t + 1 < T_STEPS)                  // vmcnt load, hidden under
                xn = xg[(size_t)(t + 1) * G4 + grow];   // the lgkmcnt-only spin
            const uint32_t fw = (uint32_t)(t + 1);
            for (;;) {
                uint32_t f = (l < NW)
                    ? __hip_atomic_load(&pflag[p][l], __ATOMIC_ACQUIRE,
                                        __HIP_MEMORY_SCOPE_WORKGROUP)
                    : fw;
                if (__all(f == fw)) break;
            }
            float s0 = 0.f, s1 = 0.f, s2 = 0.f, s3 = 0.f;
#pragma unroll
            for (int ww = 0; ww < NW; ww += 4) {
                s0 += part[p][ww + 0][l];
                s1 += part[p][ww + 1][l];
                s2 += part[p][ww + 2][l];
                s3 += part[p][ww + 3][l];
            }
            float pre = ((s0 + s1) + (s2 + s3)) + xv;
            // quad exchange: every lane of a quad gets all 4 gate pre-acts
            float pi = quad_bcast<0x00>(pre);
            float pf = quad_bcast<0x55>(pre);
            float pg = quad_bcast<0xAA>(pre);
            float po = quad_bcast<0xFF>(pre);
            float ig = sigm_f(pi), fg = sigm_f(pf);
            float gv = tanh_f(pg), og = sigm_f(po);
            c = fg * c + ig * gv;                 // identical across quad
            float h = og * tanh_f(c);
            const uint32_t tag = (uint32_t)(t + 1);
            if (gate == 0) {                      // 16 lanes, one 128B line
                u64 pub = ((u64)tag << 32) | (u64)__float_as_uint(h);
                // RMW publish: performed at the LLC, leaves the line
                // allocated-dirty there (no HBM write-through). Result
                // discarded — fire-and-forget global_atomic_swap_x2.
                (void)__hip_atomic_exchange(
                    &hdata[((size_t)p << 10) + b * NW + h16], pub,
                    __ATOMIC_RELAXED, __HIP_MEMORY_SCOPE_AGENT);
                hs[(size_t)(t + 1) * HID + b * NW + h16] = h;  // epilogue copy
            }
            xv = xn;
        }
    }
}

// ---------------------------------------------------------------------------
// Kernel 3: logits = hs @ W_lin^T + b_lin ; softmax over O=2. (unchanged)
// ---------------------------------------------------------------------------
__global__ __launch_bounds__(256) void proj_softmax(
    const float* __restrict__ hs,    // [(T+1)][1024], rows 1..T are h_t
    const float* __restrict__ Wl,    // [2][1024]
    const float* __restrict__ bl,    // [2]
    float* __restrict__ out)         // [T][2]
{
    const int tid = threadIdx.x;
    const int w = tid >> 6, l = tid & 63;
    const int row = blockIdx.x * 4 + w;            // 0..8191
    const float* h = &hs[(size_t)(row + 1) * HID];

    float a0 = 0.f, a1 = 0.f;
#pragma unroll
    for (int i = 0; i < 4; ++i) {
        float4 hv = *(const float4*)&h[256 * i + 4 * l];
        float4 w0 = *(const float4*)&Wl[256 * i + 4 * l];
        float4 w1 = *(const float4*)&Wl[HID + 256 * i + 4 * l];
        a0 = fmaf(hv.x, w0.x, a0); a0 = fmaf(hv.y, w0.y, a0);
        a0 = fmaf(hv.z, w0.z, a0); a0 = fmaf(hv.w, w0.w, a0);
        a1 = fmaf(hv.x, w1.x, a1); a1 = fmaf(hv.y, w1.y, a1);
        a1 = fmaf(hv.z, w1.z, a1); a1 = fmaf(hv.w, w1.w, a1);
    }
#pragma unroll
    for (int off = 1; off < 64; off <<= 1) {
        a0 += __shfl_xor(a0, off, 64);
        a1 += __shfl_xor(a1, off, 64);
    }
    if (l == 0) {
        float l0 = a0 + bl[0];
        float l1 = a1 + bl[1];
        float m  = fmaxf(l0, l1);
        float e0 = __expf(l0 - m), e1 = __expf(l1 - m);
        float inv = 1.f / (e0 + e1);
        float2 o = make_float2(e0 * inv, e1 * inv);
        *(float2*)&out[(size_t)row * 2] = o;
    }
}

// ---------------------------------------------------------------------------
extern "C" void kernel_launch(void* const* d_in, const int* in_sizes, int n_in,
                              void* d_out, int out_size, void* d_ws, size_t ws_size,
                              hipStream_t stream)
{
    const float* input = (const float*)d_in[0];   // [8192][512]
    const float* W_ih  = (const float*)d_in[1];   // [4096][512]
    const float* W_hh  = (const float*)d_in[2];   // [4096][1024]
    const float* b_ih  = (const float*)d_in[3];   // [4096]
    const float* b_hh  = (const float*)d_in[4];   // [4096]
    const float* W_lin = (const float*)d_in[5];   // [2][1024]
    const float* b_lin = (const float*)d_in[6];   // [2]
    float* out = (float*)d_out;                   // [8192][2]

    char* ws = (char*)d_ws;
    float* hs     = (float*)ws;                          // (T+1)*1024 f32
    size_t hs_b   = (size_t)(T_STEPS + 1) * HID * sizeof(float);
    u64*   hdata  = (u64*)(ws + hs_b);                   // 2*1024 u64
    size_t hd_b   = 2 * 1024 * sizeof(u64);
    float* xg     = (float*)(ws + hs_b + hd_b);          // T*4096 f32

    // No memsets needed: 0xAA poison (0xAAAAAAAA) never equals a valid tag
    // (1..8192), hs row 0 is never read, and t=0 uses in-register zeros.

    dim3 g1(G4 / 128, T_STEPS / 128);
    gemm_xgates<<<g1, 256, 0, stream>>>(input, W_ih, b_ih, b_hh, xg);

    lstm_rec<<<NBLK, NW * 64, 0, stream>>>(W_hh, xg, hs, hdata);

    proj_softmax<<<T_STEPS / 4, 256, 0, stream>>>(hs, W_lin, b_lin, out);
}